// Round 6
// baseline (445.643 us; speedup 1.0000x reference)
//
#include <hip/hip_runtime.h>

#define Tn   2048
#define Dn   1024
#define KDn  256
#define NHn  16
#define NKVn 4
#define Rn   4096   // B*T

typedef short bf16x8 __attribute__((ext_vector_type(8)));
typedef float f32x4  __attribute__((ext_vector_type(4)));

// ---- device-global intermediates; referenced ONLY from device code ---------
__device__ unsigned short g_q[(size_t)Rn * Dn];              // 8 MB [b][t][h][d]
__device__ unsigned short g_k[(size_t)Rn * KDn];             // 2 MB [b][t][kvh][d]
__device__ unsigned short g_vt[(size_t)2 * NKVn * 64 * Tn];  // 2 MB [b][kvh][d][t]
__device__ unsigned short g_y[(size_t)Rn * Dn];              // 8 MB [b][t][h][d]
__device__ float g_tq[Rn * 8];
__device__ float g_tv[Rn * 8];

static __device__ __forceinline__ float bf2f(unsigned short u) {
    return __uint_as_float(((unsigned)u) << 16);
}
static __device__ __forceinline__ unsigned short f2bf(float f) {
    unsigned u = __float_as_uint(f);
    u += 0x7fffu + ((u >> 16) & 1u);   // round-to-nearest-even
    return (unsigned short)(u >> 16);
}
static __device__ __forceinline__ unsigned pk2bf(float a, float b) {
    return (unsigned)f2bf(a) | ((unsigned)f2bf(b) << 16);
}
static __device__ __forceinline__ float wave_sum(float s) {
    #pragma unroll
    for (int off = 32; off; off >>= 1) s += __shfl_xor(s, off);
    return s;
}
// load 8 fp32, round to bf16, store 16B into LDS
static __device__ __forceinline__ void stage8(unsigned short* dst, const float* src) {
    float4 a = *(const float4*)src;
    float4 b = *(const float4*)(src + 4);
    unsigned short t8[8] = {f2bf(a.x), f2bf(a.y), f2bf(a.z), f2bf(a.w),
                            f2bf(b.x), f2bf(b.y), f2bf(b.z), f2bf(b.w)};
    *(uint4*)dst = *(const uint4*)t8;
}

// ---------------- LoRA temporaries: tq = x@Aq^T, tv = x@Av^T ----------------
__global__ __launch_bounds__(256)
void lora_tmp(const float* __restrict__ x,
              const float* __restrict__ Aq,
              const float* __restrict__ Av) {
    int tid = threadIdx.x, wave = tid >> 6, lane = tid & 63;
    int row = blockIdx.x * 4 + wave;
    const float* xr = x + (size_t)row * Dn;
    float aq[8], av[8];
    #pragma unroll
    for (int r = 0; r < 8; r++) { aq[r] = 0.f; av[r] = 0.f; }
    for (int it = 0; it < Dn / 64; it++) {
        int j = lane + it * 64;
        float xv = xr[j];
        #pragma unroll
        for (int r = 0; r < 8; r++) aq[r] += xv * Aq[r * Dn + j];
        #pragma unroll
        for (int r = 0; r < 8; r++) av[r] += xv * Av[r * Dn + j];
    }
    #pragma unroll
    for (int r = 0; r < 8; r++) { aq[r] = wave_sum(aq[r]); av[r] = wave_sum(av[r]); }
    if (lane == 0) {
        #pragma unroll
        for (int r = 0; r < 8; r++) { g_tq[row * 8 + r] = aq[r]; g_tv[row * 8 + r] = av[r]; }
    }
}

// ---- MFMA GEMM: C = A(MxK) @ W(NxK)^T (+ t(Mx8) @ Bl(Nx8)^T) ---------------
// DST: 0=g_q, 1=g_k, 2=g_vt (transposed [b][kvh][d][t]), 3=Cout fp32.
// ASEL: 0=Afp (fp32), 1=g_y (bf16). TSEL: 0=g_tq, 1=g_tv.
template<int LORA, int DST, int ASEL, int TSEL>
__global__ __launch_bounds__(256, 2)
void gemm_bt(const float* __restrict__ Afp,
             const float* __restrict__ W,
             float* __restrict__ Cout,
             const float* __restrict__ Bl,
             int M, int N, int K) {
    const float* tl = (TSEL == 0) ? g_tq : g_tv;

    __shared__ __align__(16) unsigned short As[64 * 40];
    __shared__ __align__(16) unsigned short Ws[64 * 40];
    int tid = threadIdx.x;
    int w = tid >> 6, lane = tid & 63;
    int m_ = lane & 15, quad = lane >> 4;
    int n0 = blockIdx.x * 64, m0 = blockIdx.y * 64;
    int srow = tid >> 2, sseg = (tid & 3) * 8;

    f32x4 acc[4];
    #pragma unroll
    for (int i = 0; i < 4; i++) acc[i] = (f32x4){0.f, 0.f, 0.f, 0.f};

    for (int k0 = 0; k0 < K; k0 += 32) {
        __syncthreads();
        if (ASEL == 0) {
            stage8(&As[srow * 40 + sseg], Afp + (size_t)(m0 + srow) * K + k0 + sseg);
        } else {
            *(uint4*)&As[srow * 40 + sseg] =
                *(const uint4*)(g_y + (size_t)(m0 + srow) * K + k0 + sseg);
        }
        stage8(&Ws[srow * 40 + sseg], W + (size_t)(n0 + srow) * K + k0 + sseg);
        __syncthreads();
        bf16x8 af = *(const bf16x8*)&As[(w * 16 + m_) * 40 + quad * 8];
        #pragma unroll
        for (int i = 0; i < 4; i++) {
            bf16x8 bfv = *(const bf16x8*)&Ws[(i * 16 + m_) * 40 + quad * 8];
            acc[i] = __builtin_amdgcn_mfma_f32_16x16x32_bf16(af, bfv, acc[i], 0, 0, 0);
        }
    }

    float tvr[4][8], blc[4][8];
    if (LORA) {
        #pragma unroll
        for (int r = 0; r < 4; r++) {
            int row = m0 + w * 16 + quad * 4 + r;
            const float* tp = tl + (size_t)row * 8;
            #pragma unroll
            for (int j = 0; j < 8; j++) tvr[r][j] = tp[j];
        }
        #pragma unroll
        for (int i = 0; i < 4; i++) {
            int col = n0 + i * 16 + m_;
            const float* bp = Bl + (size_t)col * 8;
            #pragma unroll
            for (int j = 0; j < 8; j++) blc[i][j] = bp[j];
        }
    }
    #pragma unroll
    for (int i = 0; i < 4; i++) {
        int col = n0 + i * 16 + m_;
        #pragma unroll
        for (int r = 0; r < 4; r++) {
            int row = m0 + w * 16 + quad * 4 + r;
            float val = acc[i][r];
            if (LORA) {
                #pragma unroll
                for (int j = 0; j < 8; j++) val += tvr[r][j] * blc[i][j];
            }
            if (DST == 3) {
                Cout[(size_t)row * N + col] = val;
            } else if (DST == 2) {
                // transposed V store: row=(b,t), col=(kvh,d) -> [b][kvh][d][t]
                int b = row >> 11, t = row & (Tn - 1);
                int kvh = col >> 6, d = col & 63;
                g_vt[(((size_t)(b * NKVn + kvh) * 64) + d) * Tn + t] = f2bf(val);
            } else {
                unsigned short* C = (DST == 0) ? g_q : g_k;
                C[(size_t)row * N + col] = f2bf(val);
            }
        }
    }
}

// -------- RMSNorm + partial RoPE (+gain for q), in place on g_q / g_k -------
__global__ __launch_bounds__(256)
void nrg_kernel(const float* __restrict__ gain) {
    int tid = threadIdx.x;
    int u = blockIdx.y * 4 + (tid >> 6);   // 0..15: q heads, 16..19: k heads
    int lane = tid & 63;
    int row = blockIdx.x;
    int t = row & (Tn - 1);

    unsigned short* buf;
    size_t off;
    if (u < 16) { buf = g_q; off = (size_t)row * Dn + u * 64 + lane; }
    else        { buf = g_k; off = (size_t)row * KDn + (u - 16) * 64 + lane; }

    float v = bf2f(buf[off]);
    float s = wave_sum(v * v);
    float xv = v * rsqrtf(s * (1.0f / 64.0f) + 1.1920929e-7f);
    float p = __shfl_xor(xv, 8);
    if (lane < 16) {
        int j = lane & 7;
        float fr = (float)t * exp2f(-(float)j * 1.6609640474436813f); // base^(-j/8)
        float c = cosf(fr), sn = sinf(fr);
        xv = (lane < 8) ? (xv * c + p * sn) : (p * sn - xv * c);
    }
    if (u < 16) xv *= gain[u];
    buf[off] = f2bf(xv);
}

// -------- MFMA flash attention: ONE wave per block = 16 q rows --------------
// 1-wave blocks x 4096: up to 32 waves/CU (vs 16 with 4-wave blocks) and
// fine-grained scheduling of the causal load imbalance (work ~ qb).
// S^T = K_tile(16k x 64d) . Q^T  (A=K natural rows, B=Q natural rows)
// O^T = V^T(d x keys) . P^T      (A=g_vt natural rows, B=P^T via private LDS)
__global__ __launch_bounds__(64, 8)
void attn_kernel() {
    __shared__ __align__(16) unsigned short Pt[16 * 40];  // wave-private P^T
    const float qsc = 0.125f * 1.44269504088896f;  // 1/sqrt(64) * log2(e)
    int lane = threadIdx.x;
    int q_ = lane & 15, quad = lane >> 4;
    int b = blockIdx.z, h = blockIdx.y, kvh = h >> 2;
    int qb = blockIdx.x * 16;
    int qg = qb + q_;

    // Q B-frags: B[k=d=c*32+quad*8+j][n=q_]
    const unsigned short* qrow =
        g_q + ((size_t)(b * Tn + qg) * NHn + h) * 64 + quad * 8;
    bf16x8 Qf0 = *(const bf16x8*)qrow;
    bf16x8 Qf1 = *(const bf16x8*)(qrow + 32);

    // K A-frag base: A[m=key(lane&15)][k=d(quad*8+j)]
    const unsigned short* kbase =
        g_k + ((size_t)(b * Tn + q_) * NKVn + kvh) * 64 + quad * 8;
    // V^T A-frag base: A[m=d chunk (lane&15)][k=key(quad*8+j)]
    const unsigned short* vbase =
        g_vt + ((size_t)(b * NKVn + kvh) * 64 + q_) * Tn + quad * 8;

    f32x4 accO[4];
    #pragma unroll
    for (int i = 0; i < 4; i++) accO[i] = (f32x4){0.f, 0.f, 0.f, 0.f};
    float mrun = -1e30f, lrun = 0.f;
    int ntiles = (qb + 47) >> 5;   // ceil((qb+16)/32)

    for (int kt = 0; kt < ntiles; kt++) {
        const unsigned short* kp = kbase + (size_t)kt * (32 * NKVn * 64);
        bf16x8 k00 = *(const bf16x8*)(kp);
        bf16x8 k01 = *(const bf16x8*)(kp + 32);
        bf16x8 k10 = *(const bf16x8*)(kp + 16 * NKVn * 64);
        bf16x8 k11 = *(const bf16x8*)(kp + 16 * NKVn * 64 + 32);
        f32x4 s0 = (f32x4){0.f, 0.f, 0.f, 0.f};
        f32x4 s1 = (f32x4){0.f, 0.f, 0.f, 0.f};
        s0 = __builtin_amdgcn_mfma_f32_16x16x32_bf16(k00, Qf0, s0, 0, 0, 0);
        s0 = __builtin_amdgcn_mfma_f32_16x16x32_bf16(k01, Qf1, s0, 0, 0, 0);
        s1 = __builtin_amdgcn_mfma_f32_16x16x32_bf16(k10, Qf0, s1, 0, 0, 0);
        s1 = __builtin_amdgcn_mfma_f32_16x16x32_bf16(k11, Qf1, s1, 0, 0, 0);

        if (kt == ntiles - 1) {   // only the last tile can cross the diagonal
            int k0 = kt * 32 + quad * 4;
            #pragma unroll
            for (int r = 0; r < 4; r++) {
                if (k0 + r > qg)      s0[r] = -1e30f;
                if (k0 + 16 + r > qg) s1[r] = -1e30f;
            }
        }
        float tmax = fmaxf(fmaxf(fmaxf(s0[0], s0[1]), fmaxf(s0[2], s0[3])),
                           fmaxf(fmaxf(s1[0], s1[1]), fmaxf(s1[2], s1[3])));
        tmax = fmaxf(tmax, __shfl_xor(tmax, 16));
        tmax = fmaxf(tmax, __shfl_xor(tmax, 32));
        float mn = fmaxf(mrun, tmax);
        float alpha = exp2f((mrun - mn) * qsc);
        float p0[4], p1[4], ps = 0.f;
        #pragma unroll
        for (int r = 0; r < 4; r++) { p0[r] = exp2f((s0[r] - mn) * qsc); ps += p0[r]; }
        #pragma unroll
        for (int r = 0; r < 4; r++) { p1[r] = exp2f((s1[r] - mn) * qsc); ps += p1[r]; }
        ps += __shfl_xor(ps, 16);
        ps += __shfl_xor(ps, 32);
        lrun = lrun * alpha + ps;
        mrun = mn;
        #pragma unroll
        for (int i = 0; i < 4; i++)
            #pragma unroll
            for (int r = 0; r < 4; r++) accO[i][r] *= alpha;

        // P^T to wave-private LDS (keys quad*4.. and 16+quad*4..), read B-frag
        uint2 w0 = make_uint2(pk2bf(p0[0], p0[1]), pk2bf(p0[2], p0[3]));
        uint2 w1 = make_uint2(pk2bf(p1[0], p1[1]), pk2bf(p1[2], p1[3]));
        *(uint2*)&Pt[q_ * 40 + quad * 4] = w0;
        *(uint2*)&Pt[q_ * 40 + 16 + quad * 4] = w1;
        bf16x8 pf = *(const bf16x8*)&Pt[q_ * 40 + quad * 8];

        const unsigned short* vp = vbase + kt * 32;
        #pragma unroll
        for (int c = 0; c < 4; c++) {
            bf16x8 vf = *(const bf16x8*)(vp + (size_t)c * 16 * Tn);
            accO[c] = __builtin_amdgcn_mfma_f32_16x16x32_bf16(vf, pf, accO[c], 0, 0, 0);
        }
    }

    float invl = 1.0f / lrun;
    unsigned short* yp = g_y + ((size_t)(b * Tn + qg) * NHn + h) * 64;
    #pragma unroll
    for (int c = 0; c < 4; c++) {
        uint2 o = make_uint2(pk2bf(accO[c][0] * invl, accO[c][1] * invl),
                             pk2bf(accO[c][2] * invl, accO[c][3] * invl));
        *(uint2*)&yp[c * 16 + quad * 4] = o;
    }
}

// ----------------------------------------------------------------------------
extern "C" void kernel_launch(void* const* d_in, const int* in_sizes, int n_in,
                              void* d_out, int out_size, void* d_ws, size_t ws_size,
                              hipStream_t stream) {
    const float* x  = (const float*)d_in[0];
    const float* Wq = (const float*)d_in[1];
    const float* Wk = (const float*)d_in[2];
    const float* Wv = (const float*)d_in[3];
    const float* Wp = (const float*)d_in[4];
    const float* qg = (const float*)d_in[5];
    const float* Aq = (const float*)d_in[6];
    const float* Bq = (const float*)d_in[7];
    const float* Av = (const float*)d_in[8];
    const float* Bv = (const float*)d_in[9];
    float* out = (float*)d_out;

    lora_tmp<<<dim3(Rn / 4), dim3(256), 0, stream>>>(x, Aq, Av);
    gemm_bt<1, 0, 0, 0><<<dim3(Dn / 64, Rn / 64), dim3(256), 0, stream>>>(
        x, Wq, nullptr, Bq, Rn, Dn, Dn);
    gemm_bt<0, 1, 0, 0><<<dim3(KDn / 64, Rn / 64), dim3(256), 0, stream>>>(
        x, Wk, nullptr, nullptr, Rn, KDn, Dn);
    gemm_bt<1, 2, 0, 1><<<dim3(KDn / 64, Rn / 64), dim3(256), 0, stream>>>(
        x, Wv, nullptr, Bv, Rn, KDn, Dn);
    nrg_kernel<<<dim3(Rn, 5), dim3(256), 0, stream>>>(qg);
    attn_kernel<<<dim3(Tn / 16, NHn, 2), dim3(64), 0, stream>>>();
    gemm_bt<0, 3, 1, 0><<<dim3(Dn / 64, Rn / 64), dim3(256), 0, stream>>>(
        nullptr, Wp, out, nullptr, Rn, Dn, Dn);
}

// Round 7
// 440.229 us; speedup vs baseline: 1.0123x; 1.0123x over previous
//
#include <hip/hip_runtime.h>

#define Tn   2048
#define Dn   1024
#define KDn  256
#define NHn  16
#define NKVn 4
#define Rn   4096   // B*T

typedef short bf16x8 __attribute__((ext_vector_type(8)));
typedef float f32x4  __attribute__((ext_vector_type(4)));

// ---- device-global intermediates; referenced ONLY from device code ---------
__device__ unsigned short g_q[(size_t)Rn * Dn];              // 8 MB [b][t][h][d]
__device__ unsigned short g_k[(size_t)Rn * KDn];             // 2 MB [b][t][kvh][d]
__device__ unsigned short g_vt[(size_t)2 * NKVn * 64 * Tn];  // 2 MB [b][kvh][d][t]
__device__ unsigned short g_y[(size_t)Rn * Dn];              // 8 MB [b][t][h][d]
__device__ float g_tq[Rn * 8];
__device__ float g_tv[Rn * 8];

static __device__ __forceinline__ float bf2f(unsigned short u) {
    return __uint_as_float(((unsigned)u) << 16);
}
static __device__ __forceinline__ unsigned short f2bf(float f) {
    unsigned u = __float_as_uint(f);
    u += 0x7fffu + ((u >> 16) & 1u);   // round-to-nearest-even
    return (unsigned short)(u >> 16);
}
static __device__ __forceinline__ unsigned pk2bf(float a, float b) {
    return (unsigned)f2bf(a) | ((unsigned)f2bf(b) << 16);
}
static __device__ __forceinline__ float wave_sum(float s) {
    #pragma unroll
    for (int off = 32; off; off >>= 1) s += __shfl_xor(s, off);
    return s;
}
// load 8 fp32, round to bf16, store 16B into LDS
static __device__ __forceinline__ void stage8(unsigned short* dst, const float* src) {
    float4 a = *(const float4*)src;
    float4 b = *(const float4*)(src + 4);
    unsigned short t8[8] = {f2bf(a.x), f2bf(a.y), f2bf(a.z), f2bf(a.w),
                            f2bf(b.x), f2bf(b.y), f2bf(b.z), f2bf(b.w)};
    *(uint4*)dst = *(const uint4*)t8;
}

// ---------------- LoRA temporaries: tq = x@Aq^T, tv = x@Av^T ----------------
__global__ __launch_bounds__(256)
void lora_tmp(const float* __restrict__ x,
              const float* __restrict__ Aq,
              const float* __restrict__ Av) {
    int tid = threadIdx.x, wave = tid >> 6, lane = tid & 63;
    int row = blockIdx.x * 4 + wave;
    const float* xr = x + (size_t)row * Dn;
    float aq[8], av[8];
    #pragma unroll
    for (int r = 0; r < 8; r++) { aq[r] = 0.f; av[r] = 0.f; }
    for (int it = 0; it < Dn / 64; it++) {
        int j = lane + it * 64;
        float xv = xr[j];
        #pragma unroll
        for (int r = 0; r < 8; r++) aq[r] += xv * Aq[r * Dn + j];
        #pragma unroll
        for (int r = 0; r < 8; r++) av[r] += xv * Av[r * Dn + j];
    }
    #pragma unroll
    for (int r = 0; r < 8; r++) { aq[r] = wave_sum(aq[r]); av[r] = wave_sum(av[r]); }
    if (lane == 0) {
        #pragma unroll
        for (int r = 0; r < 8; r++) { g_tq[row * 8 + r] = aq[r]; g_tv[row * 8 + r] = av[r]; }
    }
}

// ---- MFMA GEMM: C = A(MxK) @ W(NxK)^T (+ t(Mx8) @ Bl(Nx8)^T) ---------------
// DST: 0=g_q, 1=g_k, 2=g_vt (transposed [b][kvh][d][t]), 3=Cout fp32.
// ASEL: 0=Afp (fp32), 1=g_y (bf16). TSEL: 0=g_tq, 1=g_tv.
template<int LORA, int DST, int ASEL, int TSEL>
__global__ __launch_bounds__(256, 2)
void gemm_bt(const float* __restrict__ Afp,
             const float* __restrict__ W,
             float* __restrict__ Cout,
             const float* __restrict__ Bl,
             int M, int N, int K) {
    const float* tl = (TSEL == 0) ? g_tq : g_tv;

    __shared__ __align__(16) unsigned short As[64 * 40];
    __shared__ __align__(16) unsigned short Ws[64 * 40];
    int tid = threadIdx.x;
    int w = tid >> 6, lane = tid & 63;
    int m_ = lane & 15, quad = lane >> 4;
    int n0 = blockIdx.x * 64, m0 = blockIdx.y * 64;
    int srow = tid >> 2, sseg = (tid & 3) * 8;

    f32x4 acc[4];
    #pragma unroll
    for (int i = 0; i < 4; i++) acc[i] = (f32x4){0.f, 0.f, 0.f, 0.f};

    for (int k0 = 0; k0 < K; k0 += 32) {
        __syncthreads();
        if (ASEL == 0) {
            stage8(&As[srow * 40 + sseg], Afp + (size_t)(m0 + srow) * K + k0 + sseg);
        } else {
            *(uint4*)&As[srow * 40 + sseg] =
                *(const uint4*)(g_y + (size_t)(m0 + srow) * K + k0 + sseg);
        }
        stage8(&Ws[srow * 40 + sseg], W + (size_t)(n0 + srow) * K + k0 + sseg);
        __syncthreads();
        bf16x8 af = *(const bf16x8*)&As[(w * 16 + m_) * 40 + quad * 8];
        #pragma unroll
        for (int i = 0; i < 4; i++) {
            bf16x8 bfv = *(const bf16x8*)&Ws[(i * 16 + m_) * 40 + quad * 8];
            acc[i] = __builtin_amdgcn_mfma_f32_16x16x32_bf16(af, bfv, acc[i], 0, 0, 0);
        }
    }

    float tvr[4][8], blc[4][8];
    if (LORA) {
        #pragma unroll
        for (int r = 0; r < 4; r++) {
            int row = m0 + w * 16 + quad * 4 + r;
            const float* tp = tl + (size_t)row * 8;
            #pragma unroll
            for (int j = 0; j < 8; j++) tvr[r][j] = tp[j];
        }
        #pragma unroll
        for (int i = 0; i < 4; i++) {
            int col = n0 + i * 16 + m_;
            const float* bp = Bl + (size_t)col * 8;
            #pragma unroll
            for (int j = 0; j < 8; j++) blc[i][j] = bp[j];
        }
    }
    #pragma unroll
    for (int i = 0; i < 4; i++) {
        int col = n0 + i * 16 + m_;
        #pragma unroll
        for (int r = 0; r < 4; r++) {
            int row = m0 + w * 16 + quad * 4 + r;
            float val = acc[i][r];
            if (LORA) {
                #pragma unroll
                for (int j = 0; j < 8; j++) val += tvr[r][j] * blc[i][j];
            }
            if (DST == 3) {
                Cout[(size_t)row * N + col] = val;
            } else if (DST == 2) {
                // transposed V store: row=(b,t), col=(kvh,d) -> [b][kvh][d][t]
                int b = row >> 11, t = row & (Tn - 1);
                int kvh = col >> 6, d = col & 63;
                g_vt[(((size_t)(b * NKVn + kvh) * 64) + d) * Tn + t] = f2bf(val);
            } else {
                unsigned short* C = (DST == 0) ? g_q : g_k;
                C[(size_t)row * N + col] = f2bf(val);
            }
        }
    }
}

// -------- RMSNorm + partial RoPE (+gain for q), in place on g_q / g_k -------
__global__ __launch_bounds__(256)
void nrg_kernel(const float* __restrict__ gain) {
    int tid = threadIdx.x;
    int u = blockIdx.y * 4 + (tid >> 6);   // 0..15: q heads, 16..19: k heads
    int lane = tid & 63;
    int row = blockIdx.x;
    int t = row & (Tn - 1);

    unsigned short* buf;
    size_t off;
    if (u < 16) { buf = g_q; off = (size_t)row * Dn + u * 64 + lane; }
    else        { buf = g_k; off = (size_t)row * KDn + (u - 16) * 64 + lane; }

    float v = bf2f(buf[off]);
    float s = wave_sum(v * v);
    float xv = v * rsqrtf(s * (1.0f / 64.0f) + 1.1920929e-7f);
    float p = __shfl_xor(xv, 8);
    if (lane < 16) {
        int j = lane & 7;
        float fr = (float)t * exp2f(-(float)j * 1.6609640474436813f); // base^(-j/8)
        float c = cosf(fr), sn = sinf(fr);
        xv = (lane < 8) ? (xv * c + p * sn) : (p * sn - xv * c);
    }
    if (u < 16) xv *= gain[u];
    buf[off] = f2bf(xv);
}

// -------- MFMA flash attention, STATIC softmax (no running max) -------------
// Bound: |S*scale*log2e| <= ||q||*||k||*0.1803 = 42*8*0.1803 = 60.6 < 127,
// so 2^S, l, accO all stay finite in fp32/bf16 — no max tracking, no accO
// rescale, no per-tile shuffles. l reduced across quads ONCE at the end.
// Prefetch: V(kt) issued before S-MFMA; K(kt+1) double-buffered in registers.
__global__ __launch_bounds__(64, 4)
void attn_kernel() {
    __shared__ __align__(16) unsigned short Pt[16 * 40];  // wave-private P^T
    const float qsc = 0.125f * 1.44269504088896f;  // 1/sqrt(64) * log2(e)
    int lane = threadIdx.x;
    int q_ = lane & 15, quad = lane >> 4;
    int b = blockIdx.z, h = blockIdx.y, kvh = h >> 2;
    int qb = blockIdx.x * 16;
    int qg = qb + q_;

    // Q B-frags: B[k=d=c*32+quad*8+j][n=q_]
    const unsigned short* qrow =
        g_q + ((size_t)(b * Tn + qg) * NHn + h) * 64 + quad * 8;
    bf16x8 Qf0 = *(const bf16x8*)qrow;
    bf16x8 Qf1 = *(const bf16x8*)(qrow + 32);

    // K A-frag base: A[m=key(lane&15)][k=d(quad*8+j)]
    const unsigned short* kbase =
        g_k + ((size_t)(b * Tn + q_) * NKVn + kvh) * 64 + quad * 8;
    // V^T A-frag base: A[m=d chunk (lane&15)][k=key(quad*8+j)]
    const unsigned short* vbase =
        g_vt + ((size_t)(b * NKVn + kvh) * 64 + q_) * Tn + quad * 8;

    f32x4 accO[4];
    #pragma unroll
    for (int i = 0; i < 4; i++) accO[i] = (f32x4){0.f, 0.f, 0.f, 0.f};
    float lsum = 0.f;
    int ntiles = (qb + 47) >> 5;   // ceil((qb+16)/32)
    const int kstride = 32 * NKVn * 64;

    // preload K tile 0
    bf16x8 k00 = *(const bf16x8*)(kbase);
    bf16x8 k01 = *(const bf16x8*)(kbase + 32);
    bf16x8 k10 = *(const bf16x8*)(kbase + 16 * NKVn * 64);
    bf16x8 k11 = *(const bf16x8*)(kbase + 16 * NKVn * 64 + 32);

    for (int kt = 0; kt < ntiles; kt++) {
        // issue V loads for this tile first (independent of everything)
        const unsigned short* vp = vbase + kt * 32;
        bf16x8 v0 = *(const bf16x8*)(vp);
        bf16x8 v1 = *(const bf16x8*)(vp + (size_t)16 * Tn);
        bf16x8 v2 = *(const bf16x8*)(vp + (size_t)32 * Tn);
        bf16x8 v3 = *(const bf16x8*)(vp + (size_t)48 * Tn);

        f32x4 s0 = (f32x4){0.f, 0.f, 0.f, 0.f};
        f32x4 s1 = (f32x4){0.f, 0.f, 0.f, 0.f};
        s0 = __builtin_amdgcn_mfma_f32_16x16x32_bf16(k00, Qf0, s0, 0, 0, 0);
        s0 = __builtin_amdgcn_mfma_f32_16x16x32_bf16(k01, Qf1, s0, 0, 0, 0);
        s1 = __builtin_amdgcn_mfma_f32_16x16x32_bf16(k10, Qf0, s1, 0, 0, 0);
        s1 = __builtin_amdgcn_mfma_f32_16x16x32_bf16(k11, Qf1, s1, 0, 0, 0);

        // prefetch next K tile (clamped; overlaps softmax + LDS + PV below)
        {
            int ktn = (kt + 1 < ntiles) ? kt + 1 : ntiles - 1;
            const unsigned short* kp = kbase + (size_t)ktn * kstride;
            k00 = *(const bf16x8*)(kp);
            k01 = *(const bf16x8*)(kp + 32);
            k10 = *(const bf16x8*)(kp + 16 * NKVn * 64);
            k11 = *(const bf16x8*)(kp + 16 * NKVn * 64 + 32);
        }

        if (kt == ntiles - 1) {   // only the last tile can cross the diagonal
            int k0 = kt * 32 + quad * 4;
            #pragma unroll
            for (int r = 0; r < 4; r++) {
                if (k0 + r > qg)      s0[r] = -1e30f;
                if (k0 + 16 + r > qg) s1[r] = -1e30f;
            }
        }
        // static softmax: p = 2^(S*qsc); masked -> exact 0 underflow
        float p0[4], p1[4];
        #pragma unroll
        for (int r = 0; r < 4; r++) { p0[r] = exp2f(s0[r] * qsc); lsum += p0[r]; }
        #pragma unroll
        for (int r = 0; r < 4; r++) { p1[r] = exp2f(s1[r] * qsc); lsum += p1[r]; }

        // P^T to wave-private LDS (keys quad*4.. and 16+quad*4..), read B-frag
        uint2 w0 = make_uint2(pk2bf(p0[0], p0[1]), pk2bf(p0[2], p0[3]));
        uint2 w1 = make_uint2(pk2bf(p1[0], p1[1]), pk2bf(p1[2], p1[3]));
        *(uint2*)&Pt[q_ * 40 + quad * 4] = w0;
        *(uint2*)&Pt[q_ * 40 + 16 + quad * 4] = w1;
        bf16x8 pf = *(const bf16x8*)&Pt[q_ * 40 + quad * 8];

        accO[0] = __builtin_amdgcn_mfma_f32_16x16x32_bf16(v0, pf, accO[0], 0, 0, 0);
        accO[1] = __builtin_amdgcn_mfma_f32_16x16x32_bf16(v1, pf, accO[1], 0, 0, 0);
        accO[2] = __builtin_amdgcn_mfma_f32_16x16x32_bf16(v2, pf, accO[2], 0, 0, 0);
        accO[3] = __builtin_amdgcn_mfma_f32_16x16x32_bf16(v3, pf, accO[3], 0, 0, 0);
    }

    // reduce l across the 4 quads (they hold disjoint key subsets)
    lsum += __shfl_xor(lsum, 16);
    lsum += __shfl_xor(lsum, 32);
    float invl = 1.0f / lsum;
    unsigned short* yp = g_y + ((size_t)(b * Tn + qg) * NHn + h) * 64;
    #pragma unroll
    for (int c = 0; c < 4; c++) {
        uint2 o = make_uint2(pk2bf(accO[c][0] * invl, accO[c][1] * invl),
                             pk2bf(accO[c][2] * invl, accO[c][3] * invl));
        *(uint2*)&yp[c * 16 + quad * 4] = o;
    }
}

// ----------------------------------------------------------------------------
extern "C" void kernel_launch(void* const* d_in, const int* in_sizes, int n_in,
                              void* d_out, int out_size, void* d_ws, size_t ws_size,
                              hipStream_t stream) {
    const float* x  = (const float*)d_in[0];
    const float* Wq = (const float*)d_in[1];
    const float* Wk = (const float*)d_in[2];
    const float* Wv = (const float*)d_in[3];
    const float* Wp = (const float*)d_in[4];
    const float* qg = (const float*)d_in[5];
    const float* Aq = (const float*)d_in[6];
    const float* Bq = (const float*)d_in[7];
    const float* Av = (const float*)d_in[8];
    const float* Bv = (const float*)d_in[9];
    float* out = (float*)d_out;

    lora_tmp<<<dim3(Rn / 4), dim3(256), 0, stream>>>(x, Aq, Av);
    gemm_bt<1, 0, 0, 0><<<dim3(Dn / 64, Rn / 64), dim3(256), 0, stream>>>(
        x, Wq, nullptr, Bq, Rn, Dn, Dn);
    gemm_bt<0, 1, 0, 0><<<dim3(KDn / 64, Rn / 64), dim3(256), 0, stream>>>(
        x, Wk, nullptr, nullptr, Rn, KDn, Dn);
    gemm_bt<1, 2, 0, 1><<<dim3(KDn / 64, Rn / 64), dim3(256), 0, stream>>>(
        x, Wv, nullptr, Bv, Rn, KDn, Dn);
    nrg_kernel<<<dim3(Rn, 5), dim3(256), 0, stream>>>(qg);
    attn_kernel<<<dim3(Tn / 16, NHn, 2), dim3(64), 0, stream>>>();
    gemm_bt<0, 3, 1, 0><<<dim3(Dn / 64, Rn / 64), dim3(256), 0, stream>>>(
        nullptr, Wp, out, nullptr, Rn, Dn, Dn);
}

// Round 8
// 289.316 us; speedup vs baseline: 1.5403x; 1.5216x over previous
//
#include <hip/hip_runtime.h>

#define Tn   2048
#define Dn   1024
#define KDn  256
#define NHn  16
#define NKVn 4
#define Rn   4096   // B*T

typedef short bf16x8 __attribute__((ext_vector_type(8)));
typedef float f32x4  __attribute__((ext_vector_type(4)));

// ---- device-global intermediates; referenced ONLY from device code ---------
__device__ unsigned short g_q[(size_t)Rn * Dn];              // 8 MB [b][t][h][d]
__device__ unsigned short g_k[(size_t)Rn * KDn];             // 2 MB [b][t][kvh][d]
__device__ unsigned short g_vt[(size_t)2 * NKVn * 64 * Tn];  // 2 MB [b][kvh][d][t]
__device__ unsigned short g_y[(size_t)Rn * Dn];              // 8 MB [b][t][h][d]
__device__ float g_tq[Rn * 8];
__device__ float g_tv[Rn * 8];

static __device__ __forceinline__ float bf2f(unsigned short u) {
    return __uint_as_float(((unsigned)u) << 16);
}
static __device__ __forceinline__ unsigned short f2bf(float f) {
    unsigned u = __float_as_uint(f);
    u += 0x7fffu + ((u >> 16) & 1u);   // round-to-nearest-even
    return (unsigned short)(u >> 16);
}
static __device__ __forceinline__ unsigned pk2bf(float a, float b) {
    return (unsigned)f2bf(a) | ((unsigned)f2bf(b) << 16);
}
static __device__ __forceinline__ float wave_sum(float s) {
    #pragma unroll
    for (int off = 32; off; off >>= 1) s += __shfl_xor(s, off);
    return s;
}
// load 8 fp32, round to bf16, store 16B into LDS
static __device__ __forceinline__ void stage8(unsigned short* dst, const float* src) {
    float4 a = *(const float4*)src;
    float4 b = *(const float4*)(src + 4);
    unsigned short t8[8] = {f2bf(a.x), f2bf(a.y), f2bf(a.z), f2bf(a.w),
                            f2bf(b.x), f2bf(b.y), f2bf(b.z), f2bf(b.w)};
    *(uint4*)dst = *(const uint4*)t8;
}

// ---------------- LoRA temporaries: tq = x@Aq^T, tv = x@Av^T ----------------
__global__ __launch_bounds__(256)
void lora_tmp(const float* __restrict__ x,
              const float* __restrict__ Aq,
              const float* __restrict__ Av) {
    int tid = threadIdx.x, wave = tid >> 6, lane = tid & 63;
    int row = blockIdx.x * 4 + wave;
    const float* xr = x + (size_t)row * Dn;
    float aq[8], av[8];
    #pragma unroll
    for (int r = 0; r < 8; r++) { aq[r] = 0.f; av[r] = 0.f; }
    for (int it = 0; it < Dn / 64; it++) {
        int j = lane + it * 64;
        float xv = xr[j];
        #pragma unroll
        for (int r = 0; r < 8; r++) aq[r] += xv * Aq[r * Dn + j];
        #pragma unroll
        for (int r = 0; r < 8; r++) av[r] += xv * Av[r * Dn + j];
    }
    #pragma unroll
    for (int r = 0; r < 8; r++) { aq[r] = wave_sum(aq[r]); av[r] = wave_sum(av[r]); }
    if (lane == 0) {
        #pragma unroll
        for (int r = 0; r < 8; r++) { g_tq[row * 8 + r] = aq[r]; g_tv[row * 8 + r] = av[r]; }
    }
}

// ---- MFMA GEMM: C = A(MxK) @ W(NxK)^T (+ t(Mx8) @ Bl(Nx8)^T) ---------------
// DST: 0=g_q, 1=g_k, 2=g_vt (transposed [b][kvh][d][t]), 3=Cout fp32.
// ASEL: 0=Afp (fp32), 1=g_y (bf16). TSEL: 0=g_tq, 1=g_tv.
template<int LORA, int DST, int ASEL, int TSEL>
__global__ __launch_bounds__(256, 2)
void gemm_bt(const float* __restrict__ Afp,
             const float* __restrict__ W,
             float* __restrict__ Cout,
             const float* __restrict__ Bl,
             int M, int N, int K) {
    const float* tl = (TSEL == 0) ? g_tq : g_tv;

    __shared__ __align__(16) unsigned short As[64 * 40];
    __shared__ __align__(16) unsigned short Ws[64 * 40];
    int tid = threadIdx.x;
    int w = tid >> 6, lane = tid & 63;
    int m_ = lane & 15, quad = lane >> 4;
    int n0 = blockIdx.x * 64, m0 = blockIdx.y * 64;
    int srow = tid >> 2, sseg = (tid & 3) * 8;

    f32x4 acc[4];
    #pragma unroll
    for (int i = 0; i < 4; i++) acc[i] = (f32x4){0.f, 0.f, 0.f, 0.f};

    for (int k0 = 0; k0 < K; k0 += 32) {
        __syncthreads();
        if (ASEL == 0) {
            stage8(&As[srow * 40 + sseg], Afp + (size_t)(m0 + srow) * K + k0 + sseg);
        } else {
            *(uint4*)&As[srow * 40 + sseg] =
                *(const uint4*)(g_y + (size_t)(m0 + srow) * K + k0 + sseg);
        }
        stage8(&Ws[srow * 40 + sseg], W + (size_t)(n0 + srow) * K + k0 + sseg);
        __syncthreads();
        bf16x8 af = *(const bf16x8*)&As[(w * 16 + m_) * 40 + quad * 8];
        #pragma unroll
        for (int i = 0; i < 4; i++) {
            bf16x8 bfv = *(const bf16x8*)&Ws[(i * 16 + m_) * 40 + quad * 8];
            acc[i] = __builtin_amdgcn_mfma_f32_16x16x32_bf16(af, bfv, acc[i], 0, 0, 0);
        }
    }

    float tvr[4][8], blc[4][8];
    if (LORA) {
        #pragma unroll
        for (int r = 0; r < 4; r++) {
            int row = m0 + w * 16 + quad * 4 + r;
            const float* tp = tl + (size_t)row * 8;
            #pragma unroll
            for (int j = 0; j < 8; j++) tvr[r][j] = tp[j];
        }
        #pragma unroll
        for (int i = 0; i < 4; i++) {
            int col = n0 + i * 16 + m_;
            const float* bp = Bl + (size_t)col * 8;
            #pragma unroll
            for (int j = 0; j < 8; j++) blc[i][j] = bp[j];
        }
    }
    #pragma unroll
    for (int i = 0; i < 4; i++) {
        int col = n0 + i * 16 + m_;
        #pragma unroll
        for (int r = 0; r < 4; r++) {
            int row = m0 + w * 16 + quad * 4 + r;
            float val = acc[i][r];
            if (LORA) {
                #pragma unroll
                for (int j = 0; j < 8; j++) val += tvr[r][j] * blc[i][j];
            }
            if (DST == 3) {
                Cout[(size_t)row * N + col] = val;
            } else if (DST == 2) {
                // transposed V store: row=(b,t), col=(kvh,d) -> [b][kvh][d][t]
                int b = row >> 11, t = row & (Tn - 1);
                int kvh = col >> 6, d = col & 63;
                g_vt[(((size_t)(b * NKVn + kvh) * 64) + d) * Tn + t] = f2bf(val);
            } else {
                unsigned short* C = (DST == 0) ? g_q : g_k;
                C[(size_t)row * N + col] = f2bf(val);
            }
        }
    }
}

// -------- RMSNorm + partial RoPE (+gain for q), in place on g_q / g_k -------
__global__ __launch_bounds__(256)
void nrg_kernel(const float* __restrict__ gain) {
    int tid = threadIdx.x;
    int u = blockIdx.y * 4 + (tid >> 6);   // 0..15: q heads, 16..19: k heads
    int lane = tid & 63;
    int row = blockIdx.x;
    int t = row & (Tn - 1);

    unsigned short* buf;
    size_t off;
    if (u < 16) { buf = g_q; off = (size_t)row * Dn + u * 64 + lane; }
    else        { buf = g_k; off = (size_t)row * KDn + (u - 16) * 64 + lane; }

    float v = bf2f(buf[off]);
    float s = wave_sum(v * v);
    float xv = v * rsqrtf(s * (1.0f / 64.0f) + 1.1920929e-7f);
    float p = __shfl_xor(xv, 8);
    if (lane < 16) {
        int j = lane & 7;
        float fr = (float)t * exp2f(-(float)j * 1.6609640474436813f); // base^(-j/8)
        float c = cosf(fr), sn = sinf(fr);
        xv = (lane < 8) ? (xv * c + p * sn) : (p * sn - xv * c);
    }
    if (u < 16) xv *= gain[u];
    buf[off] = f2bf(xv);
}

// -------- MFMA flash attention, block = 4 heads sharing one kv group --------
// K/V tiles staged to LDS cooperatively (double-buffered, 1 barrier/tile) so
// global-load latency overlaps MFMA compute; each wave = 1 head, 16 q rows.
// Static softmax (bound |S*qsc| <= 60.6 < 127: no running max needed).
// S^T = K_tile . Q^T ; O^T = V^T . P^T (P^T via wave-private LDS).
__global__ __launch_bounds__(256, 4)
void attn_kernel() {
    __shared__ __align__(16) unsigned short KS[2][32 * 72];  // row=key, 144B stride
    __shared__ __align__(16) unsigned short VS[2][64 * 40];  // row=d,   80B stride
    __shared__ __align__(16) unsigned short Pt[4][16 * 40];  // per-wave P^T
    const float qsc = 0.125f * 1.44269504088896f;  // 1/sqrt(64) * log2(e)
    int tid = threadIdx.x;
    int w = tid >> 6, lane = tid & 63;
    int q_ = lane & 15, quad = lane >> 4;
    int b = blockIdx.z, kvh = blockIdx.y, h = kvh * 4 + w;
    int qb = blockIdx.x * 16;
    int qg = qb + q_;

    // Q B-frags: B[k=d][n=q_]
    const unsigned short* qrow =
        g_q + ((size_t)(b * Tn + qg) * NHn + h) * 64 + quad * 8;
    bf16x8 Qf0 = *(const bf16x8*)qrow;
    bf16x8 Qf1 = *(const bf16x8*)(qrow + 32);

    // cooperative staging indices: 256 thr x 16B = one 4KB tile per issue
    int krow = tid >> 3, kseg = tid & 7;   // K: 32 rows x 8 x 16B
    int vrow = tid >> 2, vseg = tid & 3;   // V^T: 64 rows x 4 x 16B
    const unsigned short* kgp =
        g_k + ((size_t)(b * Tn + krow) * NKVn + kvh) * 64 + kseg * 8;
    const unsigned short* vgp =
        g_vt + ((size_t)(b * NKVn + kvh) * 64 + vrow) * Tn + vseg * 8;

    f32x4 accO[4];
    #pragma unroll
    for (int i = 0; i < 4; i++) accO[i] = (f32x4){0.f, 0.f, 0.f, 0.f};
    float lsum = 0.f;
    int ntiles = (qb + 47) >> 5;   // ceil((qb+16)/32); block-uniform

    // stage tile 0 into buffer 0
    {
        uint4 kr = *(const uint4*)kgp;
        uint4 vr = *(const uint4*)vgp;
        *(uint4*)&KS[0][krow * 72 + kseg * 8] = kr;
        *(uint4*)&VS[0][vrow * 40 + vseg * 8] = vr;
    }
    __syncthreads();

    for (int kt = 0; kt < ntiles; kt++) {
        int cur = kt & 1, nxt = cur ^ 1;
        // issue next-tile global loads (in flight during this tile's compute)
        uint4 krn = make_uint4(0, 0, 0, 0), vrn = make_uint4(0, 0, 0, 0);
        if (kt + 1 < ntiles) {
            krn = *(const uint4*)(kgp + (size_t)(kt + 1) * (32 * NKVn * 64));
            vrn = *(const uint4*)(vgp + (kt + 1) * 32);
        }

        const unsigned short* ks = &KS[cur][0];
        const unsigned short* vs = &VS[cur][0];
        bf16x8 k00 = *(const bf16x8*)&ks[q_ * 72 + quad * 8];
        bf16x8 k01 = *(const bf16x8*)&ks[q_ * 72 + 32 + quad * 8];
        bf16x8 k10 = *(const bf16x8*)&ks[(16 + q_) * 72 + quad * 8];
        bf16x8 k11 = *(const bf16x8*)&ks[(16 + q_) * 72 + 32 + quad * 8];
        f32x4 s0 = (f32x4){0.f, 0.f, 0.f, 0.f};
        f32x4 s1 = (f32x4){0.f, 0.f, 0.f, 0.f};
        s0 = __builtin_amdgcn_mfma_f32_16x16x32_bf16(k00, Qf0, s0, 0, 0, 0);
        s0 = __builtin_amdgcn_mfma_f32_16x16x32_bf16(k01, Qf1, s0, 0, 0, 0);
        s1 = __builtin_amdgcn_mfma_f32_16x16x32_bf16(k10, Qf0, s1, 0, 0, 0);
        s1 = __builtin_amdgcn_mfma_f32_16x16x32_bf16(k11, Qf1, s1, 0, 0, 0);

        if (kt == ntiles - 1) {   // only the last tile can cross the diagonal
            int k0 = kt * 32 + quad * 4;
            #pragma unroll
            for (int r = 0; r < 4; r++) {
                if (k0 + r > qg)      s0[r] = -1e30f;
                if (k0 + 16 + r > qg) s1[r] = -1e30f;
            }
        }
        // static softmax: p = 2^(S*qsc); masked -> exact 0 underflow
        float p0[4], p1[4];
        #pragma unroll
        for (int r = 0; r < 4; r++) { p0[r] = exp2f(s0[r] * qsc); lsum += p0[r]; }
        #pragma unroll
        for (int r = 0; r < 4; r++) { p1[r] = exp2f(s1[r] * qsc); lsum += p1[r]; }

        // P^T via wave-private LDS, read back as B-frag
        unsigned short* pb = &Pt[w][0];
        *(uint2*)&pb[q_ * 40 + quad * 4] =
            make_uint2(pk2bf(p0[0], p0[1]), pk2bf(p0[2], p0[3]));
        *(uint2*)&pb[q_ * 40 + 16 + quad * 4] =
            make_uint2(pk2bf(p1[0], p1[1]), pk2bf(p1[2], p1[3]));
        bf16x8 pf = *(const bf16x8*)&pb[q_ * 40 + quad * 8];

        #pragma unroll
        for (int c = 0; c < 4; c++) {
            bf16x8 vf = *(const bf16x8*)&vs[(c * 16 + q_) * 40 + quad * 8];
            accO[c] = __builtin_amdgcn_mfma_f32_16x16x32_bf16(vf, pf, accO[c], 0, 0, 0);
        }

        // write next tile into the other buffer, then one barrier
        if (kt + 1 < ntiles) {
            *(uint4*)&KS[nxt][krow * 72 + kseg * 8] = krn;
            *(uint4*)&VS[nxt][vrow * 40 + vseg * 8] = vrn;
        }
        __syncthreads();
    }

    // reduce l across the 4 quads (disjoint key subsets)
    lsum += __shfl_xor(lsum, 16);
    lsum += __shfl_xor(lsum, 32);
    float invl = 1.0f / lsum;
    unsigned short* yp = g_y + ((size_t)(b * Tn + qg) * NHn + h) * 64;
    #pragma unroll
    for (int c = 0; c < 4; c++) {
        uint2 o = make_uint2(pk2bf(accO[c][0] * invl, accO[c][1] * invl),
                             pk2bf(accO[c][2] * invl, accO[c][3] * invl));
        *(uint2*)&yp[c * 16 + quad * 4] = o;
    }
}

// ----------------------------------------------------------------------------
extern "C" void kernel_launch(void* const* d_in, const int* in_sizes, int n_in,
                              void* d_out, int out_size, void* d_ws, size_t ws_size,
                              hipStream_t stream) {
    const float* x  = (const float*)d_in[0];
    const float* Wq = (const float*)d_in[1];
    const float* Wk = (const float*)d_in[2];
    const float* Wv = (const float*)d_in[3];
    const float* Wp = (const float*)d_in[4];
    const float* qg = (const float*)d_in[5];
    const float* Aq = (const float*)d_in[6];
    const float* Bq = (const float*)d_in[7];
    const float* Av = (const float*)d_in[8];
    const float* Bv = (const float*)d_in[9];
    float* out = (float*)d_out;

    lora_tmp<<<dim3(Rn / 4), dim3(256), 0, stream>>>(x, Aq, Av);
    gemm_bt<1, 0, 0, 0><<<dim3(Dn / 64, Rn / 64), dim3(256), 0, stream>>>(
        x, Wq, nullptr, Bq, Rn, Dn, Dn);
    gemm_bt<0, 1, 0, 0><<<dim3(KDn / 64, Rn / 64), dim3(256), 0, stream>>>(
        x, Wk, nullptr, nullptr, Rn, KDn, Dn);
    gemm_bt<1, 2, 0, 1><<<dim3(KDn / 64, Rn / 64), dim3(256), 0, stream>>>(
        x, Wv, nullptr, Bv, Rn, KDn, Dn);
    nrg_kernel<<<dim3(Rn, 5), dim3(256), 0, stream>>>(qg);
    attn_kernel<<<dim3(Tn / 16, NKVn, 2), dim3(256), 0, stream>>>();
    gemm_bt<0, 3, 1, 0><<<dim3(Dn / 64, Rn / 64), dim3(256), 0, stream>>>(
        nullptr, Wp, out, nullptr, Rn, Dn, Dn);
}